// Round 6
// baseline (441.055 us; speedup 1.0000x reference)
//
#include <hip/hip_runtime.h>
#include <cstdint>
#include <cstddef>

// ---------------- common types / helpers ----------------
typedef __bf16 bf16x8 __attribute__((ext_vector_type(8)));
typedef __bf16 bf16x4 __attribute__((ext_vector_type(4)));
typedef float  f32x4  __attribute__((ext_vector_type(4)));
typedef float  f32x16 __attribute__((ext_vector_type(16)));

__device__ __forceinline__ void load16_to_lds(const void* g, void* l) {
  __builtin_amdgcn_global_load_lds(
      (const __attribute__((address_space(1))) void*)g,
      (__attribute__((address_space(3))) void*)l, 16, 0, 0);
}

// ---------------- weight cast+transpose: f32 (K,N) -> bf16 (N,K) ----------------
__global__ __launch_bounds__(256) void transpose_cast(
    const float* __restrict__ src, __bf16* __restrict__ dst, int K, int N)
{
  __shared__ float tile[32][33];
  const int n0 = blockIdx.x * 32, k0 = blockIdx.y * 32;
  const int tx = threadIdx.x, ty = threadIdx.y; // (32,8)
#pragma unroll
  for (int i = 0; i < 32; i += 8)
    tile[ty + i][tx] = src[(size_t)(k0 + ty + i) * N + n0 + tx];
  __syncthreads();
#pragma unroll
  for (int i = 0; i < 32; i += 8)
    dst[(size_t)(n0 + ty + i) * K + k0 + tx] = (__bf16)tile[tx][ty + i];
}

// 3x 1024x1024 in one launch (z picks the weight)
__global__ __launch_bounds__(256) void transpose_cast_qkv(
    const float* __restrict__ s0, const float* __restrict__ s1,
    const float* __restrict__ s2, __bf16* __restrict__ dst)
{
  __shared__ float tile[32][33];
  const float* src = blockIdx.z == 0 ? s0 : blockIdx.z == 1 ? s1 : s2;
  __bf16* d = dst + (size_t)blockIdx.z * 1024 * 1024;
  const int n0 = blockIdx.x * 32, k0 = blockIdx.y * 32;
  const int tx = threadIdx.x, ty = threadIdx.y; // (32,8)
#pragma unroll
  for (int i = 0; i < 32; i += 8)
    tile[ty + i][tx] = src[(size_t)(k0 + ty + i) * 1024 + n0 + tx];
  __syncthreads();
#pragma unroll
  for (int i = 0; i < 32; i += 8)
    d[(size_t)(n0 + ty + i) * 1024 + k0 + tx] = (__bf16)tile[tx][ty + i];
}

// ---------------- out init for split-K atomic GEMMs: o = a (+ bias[col]) ----
__global__ __launch_bounds__(256) void init_out(
    const float* __restrict__ a, const float* __restrict__ bias,
    float* __restrict__ o)
{
  const int i = blockIdx.x * 256 + threadIdx.x;   // float4 index, N=1024 rows
  float4 v = ((const float4*)a)[i];
  if (bias != nullptr) {
    const float4 bb = ((const float4*)bias)[i & 255];
    v.x += bb.x; v.y += bb.y; v.z += bb.z; v.w += bb.w;
  }
  ((float4*)o)[i] = v;
}

// ---------------- LayerNorm: f32 row(1024) -> bf16 ----------------
__global__ __launch_bounds__(256) void ln_kernel(
    const float* __restrict__ x, const float* __restrict__ g,
    const float* __restrict__ bta, __bf16* __restrict__ out)
{
  const int row = blockIdx.x;
  const int t = threadIdx.x;
  const float4 v = ((const float4*)(x + (size_t)row * 1024))[t];
  float s  = v.x + v.y + v.z + v.w;
  float ss = v.x * v.x + v.y * v.y + v.z * v.z + v.w * v.w;
#pragma unroll
  for (int o = 32; o > 0; o >>= 1) { s += __shfl_down(s, o); ss += __shfl_down(ss, o); }
  __shared__ float rs[4], rss[4];
  const int w = t >> 6, l = t & 63;
  if (l == 0) { rs[w] = s; rss[w] = ss; }
  __syncthreads();
  s  = rs[0] + rs[1] + rs[2] + rs[3];
  ss = rss[0] + rss[1] + rss[2] + rss[3];
  const float mu = s * (1.0f / 1024.0f);
  const float var = ss * (1.0f / 1024.0f) - mu * mu;
  const float rstd = rsqrtf(var + 1e-5f);
  const float4 gg = ((const float4*)g)[t];
  const float4 bb = ((const float4*)bta)[t];
  __bf16* o = out + (size_t)row * 1024 + t * 4;
  o[0] = (__bf16)((v.x - mu) * rstd * gg.x + bb.x);
  o[1] = (__bf16)((v.y - mu) * rstd * gg.y + bb.y);
  o[2] = (__bf16)((v.z - mu) * rstd * gg.z + bb.z);
  o[3] = (__bf16)((v.w - mu) * rstd * gg.w + bb.w);
}

// ---------------- bf16 MFMA GEMM: C = A(MxK) * Bt(NxK)^T ----------------
// Split-K via gridDim.z (SK template): block z owns K-slice [z*K/SK,(z+1)*K/SK),
// EPI_ATOMIC adds the partial into pre-initialized f32 out (init_out wrote
// res/bias) -- fixes skinny-N GEMMs (Wo/FC3) stuck at 2 blocks/CU,
// latency-bound (round-5: FC3 MfmaUtil 17 / VALU 8 / HBM 26 / occ 20).
enum { EPI_BF16 = 0, EPI_RES_F32 = 1, EPI_GELU_BF16 = 2, EPI_ATOMIC = 3 };

template <int TM, int SK, int EPI>
__global__ __launch_bounds__(256, 2) void gemm_bf16(
    const __bf16* __restrict__ A, const __bf16* __restrict__ Bt,
    __bf16* __restrict__ outb, float* __restrict__ outf,
    const float* __restrict__ bias, const float* __restrict__ res,
    int M, int N, int K)
{
  constexpr int MT = TM / 32;           // mt tiles per wave
  __shared__ __bf16 As[TM * 32];
  __shared__ __bf16 Bs[128 * 32];
  const int tid  = threadIdx.x;
  const int lane = tid & 63, w = tid >> 6;
  const int wm = w >> 1, wn = w & 1;
  const int quad = lane >> 4, l16 = lane & 15;
  const int m0 = blockIdx.y * TM, n0 = blockIdx.x * 128;
  const int Ks = K / SK;
  const int kbase = blockIdx.z * Ks;

  f32x4 acc[MT][4] = {};
  const __bf16* Ag = A  + (size_t)m0 * K + kbase;
  const __bf16* Bg = Bt + (size_t)n0 * K + kbase;

  for (int k0 = 0; k0 < Ks; k0 += 32) {
#pragma unroll
    for (int r = 0; r < TM / 64; ++r) {
      const int c = r * 256 + tid;      // TM*4 chunks of A
      const int row = c >> 2, cc = (c & 3) * 8;
      load16_to_lds(Ag + (size_t)row * K + k0 + cc, &As[c * 8]);
    }
#pragma unroll
    for (int r = 0; r < 2; ++r) {       // 512 chunks of B
      const int c = r * 256 + tid;
      const int row = c >> 2, cc = (c & 3) * 8;
      load16_to_lds(Bg + (size_t)row * K + k0 + cc, &Bs[c * 8]);
    }
    __syncthreads();
    bf16x8 af[MT], bfr[4];
#pragma unroll
    for (int mt = 0; mt < MT; ++mt)
      af[mt] = *(const bf16x8*)&As[(wm * (TM / 2) + mt * 16 + l16) * 32 + quad * 8];
#pragma unroll
    for (int nt = 0; nt < 4; ++nt)
      bfr[nt] = *(const bf16x8*)&Bs[(wn * 64 + nt * 16 + l16) * 32 + quad * 8];
#pragma unroll
    for (int mt = 0; mt < MT; ++mt)
#pragma unroll
      for (int nt = 0; nt < 4; ++nt)
        acc[mt][nt] = __builtin_amdgcn_mfma_f32_16x16x32_bf16(af[mt], bfr[nt], acc[mt][nt], 0, 0, 0);
    __syncthreads();
  }

#pragma unroll
  for (int mt = 0; mt < MT; ++mt) {
#pragma unroll
    for (int nt = 0; nt < 4; ++nt) {
      const int col = n0 + wn * 64 + nt * 16 + l16;
#pragma unroll
      for (int i = 0; i < 4; ++i) {
        const int row = m0 + wm * (TM / 2) + mt * 16 + quad * 4 + i;
        float v = acc[mt][nt][i];
        const size_t idx = (size_t)row * N + col;
        if (EPI == EPI_BF16) {
          outb[idx] = (__bf16)v;
        } else if (EPI == EPI_RES_F32) {
          outf[idx] = v + res[idx];
        } else if (EPI == EPI_GELU_BF16) {
          v += bias[col];
          outb[idx] = (__bf16)(0.5f * v * (1.0f + erff(v * 0.70710678118f)));
        } else {
          atomicAdd(&outf[idx], v);
        }
      }
    }
  }
}

// ---------------- RoPE for q,k: qkv(4096x3072) -> qr,kr [b][h][s][d] ----------------
__global__ __launch_bounds__(256) void rope_qk(
    const __bf16* __restrict__ qkv, __bf16* __restrict__ qr, __bf16* __restrict__ kr)
{
  const int idx = blockIdx.x * 256 + threadIdx.x; // (b,s,h,d2)
  const int d2 = idx & 31;
  const int h  = (idx >> 5) & 15;
  const int bs = idx >> 9;       // b*2048+s
  const int s  = bs & 2047;
  const int b  = bs >> 11;
  const float inv_freq = exp2f(-((float)d2 * (1.0f / 32.0f)) * 13.2877123795f); // log2(1e4)
  const float ang = (float)s * inv_freq;
  const float c = cosf(ang), sn = sinf(ang);
  const __bf16* qp = qkv + (size_t)bs * 3072 + h * 64 + 2 * d2;
  const __bf16* kp = qp + 1024;
  const float q0 = (float)qp[0], q1 = (float)qp[1];
  const float k0 = (float)kp[0], k1 = (float)kp[1];
  const size_t o = ((size_t)(b * 16 + h) * 2048 + s) * 64 + 2 * d2;
  qr[o]     = (__bf16)(q0 * c - q1 * sn);
  qr[o + 1] = (__bf16)(q1 * c + q0 * sn);
  kr[o]     = (__bf16)(k0 * c - k1 * sn);
  kr[o + 1] = (__bf16)(k1 * c + k0 * sn);
}

// ---------------- V transpose: qkv v-cols -> vt [b][h][d][s] ----------------
__global__ __launch_bounds__(256) void v_transpose(
    const __bf16* __restrict__ qkv, __bf16* __restrict__ vt)
{
  __shared__ __bf16 t[64][72];
  const int st = blockIdx.x, h = blockIdx.y, b = blockIdx.z;
  const int tx = threadIdx.x & 63, ty = threadIdx.x >> 6; // 64x4
  const int s0 = st * 64;
  const __bf16* src = qkv + ((size_t)(b * 2048 + s0)) * 3072 + 2048 + h * 64;
#pragma unroll
  for (int i = 0; i < 64; i += 4)
    t[ty + i][tx] = src[(size_t)(ty + i) * 3072 + tx];
  __syncthreads();
  __bf16* dst = vt + ((size_t)(b * 16 + h) * 64) * 2048 + s0;
#pragma unroll
  for (int i = 0; i < 64; i += 4)
    dst[(size_t)(ty + i) * 2048 + tx] = t[tx][ty + i];
}

// ---------------- flash attention v3: 32x32x16 MFMA, S^T orientation --------
__global__ __launch_bounds__(256, 2) void attn_kernel(
    const __bf16* __restrict__ qr, const __bf16* __restrict__ kr,
    const __bf16* __restrict__ vt, __bf16* __restrict__ attn_o)
{
  constexpr int S = 2048, DH = 64, NH = 16, BQ = 128, BKK = 64;
  __shared__ __align__(16) __bf16 smem[24576];  // 48 KB
  __bf16* Qs   = smem;                       // [128][64] swizzled; -> per-wave Pb
  __bf16* Ksb  = smem + 8192;                // 2 x [64][64] swizzled
  __bf16* Vtsb = smem + 16384;               // 2 x [64][64] swizzled

  const int tid = threadIdx.x;
  const int lane = tid & 63, w = tid >> 6;
  const int l32 = lane & 31, half = lane >> 5;
  const int qt = blockIdx.x, h = blockIdx.y, b = blockIdx.z;
  const int bh = b * NH + h;
  const __bf16* Q  = qr + ((size_t)bh * S + qt * BQ) * DH;
  const __bf16* Kp = kr + (size_t)bh * S * DH;
  const __bf16* Vp = vt + (size_t)bh * DH * S;
  __bf16* Pb = Qs + w * 2048;                // wave-local [32][64] swizzled

#pragma unroll
  for (int r4 = 0; r4 < 4; ++r4) {
    const int c = r4 * 256 + tid;
    const int r = c >> 3, cb = c & 7;
    load16_to_lds(Q + (size_t)r * DH + ((cb ^ (r & 7)) * 8), &Qs[c * 8]);
  }
#pragma unroll
  for (int r2 = 0; r2 < 2; ++r2) {
    const int c = r2 * 256 + tid;
    const int r = c >> 3, cb = c & 7;
    const int cg = (cb ^ (r & 7)) * 8;
    load16_to_lds(Kp + (size_t)r * DH + cg, &Ksb[c * 8]);
    load16_to_lds(Vp + (size_t)r * S + cg, &Vtsb[c * 8]);
  }
  __syncthreads();

  bf16x8 qfB[4];
  {
    const int row = w * 32 + l32;
#pragma unroll
    for (int c = 0; c < 4; ++c)
      qfB[c] = *(const bf16x8*)&Qs[row * 64 + (((2 * c + half) ^ (row & 7)) * 8)];
  }

  float mreg = -3.0e38f, lreg = 0.0f;
  f32x16 oacc[2] = {};

  for (int kt = 0; kt < S / BKK; ++kt) {
    if (kt) __syncthreads();
    const __bf16* Ks  = Ksb  + (kt & 1) * 4096;
    const __bf16* Vts = Vtsb + (kt & 1) * 4096;

    bf16x8 kf[2][4], vf[2][4];
#pragma unroll
    for (int t = 0; t < 2; ++t) {
      const int row = 32 * t + l32;
#pragma unroll
      for (int c = 0; c < 4; ++c)
        kf[t][c] = *(const bf16x8*)&Ks[row * 64 + (((2 * c + half) ^ (l32 & 7)) * 8)];
    }
#pragma unroll
    for (int v = 0; v < 2; ++v) {
      const int row = 32 * v + l32;
#pragma unroll
      for (int c = 0; c < 4; ++c)
        vf[v][c] = *(const bf16x8*)&Vts[row * 64 + (((2 * c + half) ^ (l32 & 7)) * 8)];
    }

    if (kt + 1 < S / BKK) {
      __bf16* Kn = Ksb  + ((kt + 1) & 1) * 4096;
      __bf16* Vn = Vtsb + ((kt + 1) & 1) * 4096;
      const size_t kk1 = (size_t)(kt + 1) * BKK;
#pragma unroll
      for (int r2 = 0; r2 < 2; ++r2) {
        const int c = r2 * 256 + tid;
        const int r = c >> 3, cb = c & 7;
        const int cg = (cb ^ (r & 7)) * 8;
        load16_to_lds(Kp + (kk1 + r) * DH + cg, &Kn[c * 8]);
        load16_to_lds(Vp + (size_t)r * S + kk1 + cg, &Vn[c * 8]);
      }
    }

    f32x16 sa[2] = {};
#pragma unroll
    for (int t = 0; t < 2; ++t)
#pragma unroll
      for (int c = 0; c < 4; ++c)
        sa[t] = __builtin_amdgcn_mfma_f32_32x32x16_bf16(kf[t][c], qfB[c], sa[t], 0, 0, 0);

    float mx = -3.0e38f;
#pragma unroll
    for (int t = 0; t < 2; ++t)
#pragma unroll
      for (int r = 0; r < 16; ++r) { sa[t][r] *= 0.125f; mx = fmaxf(mx, sa[t][r]); }
    mx = fmaxf(mx, __shfl_xor(mx, 32));
    const float mnew = fmaxf(mreg, mx);
    const float alpha = __expf(mreg - mnew);
    mreg = mnew;
    float sum = 0.0f;
#pragma unroll
    for (int t = 0; t < 2; ++t)
#pragma unroll
      for (int r = 0; r < 16; ++r) {
        const float p = __expf(sa[t][r] - mnew);
        sa[t][r] = p;
        sum += p;
      }
    sum += __shfl_xor(sum, 32);
    lreg = lreg * alpha + sum;
#pragma unroll
    for (int v = 0; v < 2; ++v)
#pragma unroll
      for (int r = 0; r < 16; ++r) oacc[v][r] *= alpha;

#pragma unroll
    for (int t = 0; t < 2; ++t)
#pragma unroll
      for (int g = 0; g < 4; ++g) {
        bf16x4 pv;
#pragma unroll
        for (int i = 0; i < 4; ++i) pv[i] = (__bf16)sa[t][4 * g + i];
        const int kc = 4 * t + g;
        *(bf16x4*)&Pb[l32 * 64 + ((kc ^ (l32 & 7)) * 8) + 4 * half] = pv;
      }

    bf16x8 pf[4];
#pragma unroll
    for (int c = 0; c < 4; ++c)
      pf[c] = *(const bf16x8*)&Pb[l32 * 64 + (((2 * c + half) ^ (l32 & 7)) * 8)];
#pragma unroll
    for (int v = 0; v < 2; ++v)
#pragma unroll
      for (int c = 0; c < 4; ++c)
        oacc[v] = __builtin_amdgcn_mfma_f32_32x32x16_bf16(vf[v][c], pf[c], oacc[v], 0, 0, 0);
  }

  const float linv = 1.0f / lreg;
#pragma unroll
  for (int v = 0; v < 2; ++v)
#pragma unroll
    for (int g = 0; g < 4; ++g) {
      bf16x4 ov;
#pragma unroll
      for (int i = 0; i < 4; ++i) ov[i] = (__bf16)(oacc[v][4 * g + i] * linv);
      const int dc = 4 * v + g;
      *(bf16x4*)&Pb[l32 * 64 + ((dc ^ (l32 & 7)) * 8) + 4 * half] = ov;
    }
#pragma unroll
  for (int cc = 0; cc < 4; ++cc) {
    const int c = cc * 64 + lane;
    const int r = c >> 3, g = c & 7;
    const bf16x8 od = *(const bf16x8*)&Pb[r * 64 + ((g ^ (r & 7)) * 8)];
    const int srow = qt * BQ + w * 32 + r;
    *(bf16x8*)&attn_o[((size_t)b * S + srow) * 1024 + h * 64 + g * 8] = od;
  }
}

// ---------------- launch ----------------
extern "C" void kernel_launch(void* const* d_in, const int* in_sizes, int n_in,
                              void* d_out, int out_size, void* d_ws, size_t ws_size,
                              hipStream_t stream) {
  const float* inputs = (const float*)d_in[0];
  const float* ln1_g  = (const float*)d_in[1];
  const float* ln1_b  = (const float*)d_in[2];
  const float* Wq     = (const float*)d_in[3];
  const float* Wk     = (const float*)d_in[4];
  const float* Wv     = (const float*)d_in[5];
  const float* Wo     = (const float*)d_in[6];
  const float* ln2_g  = (const float*)d_in[7];
  const float* ln2_b  = (const float*)d_in[8];
  const float* Wfc2   = (const float*)d_in[9];
  const float* bfc2   = (const float*)d_in[10];
  const float* Wfc3   = (const float*)d_in[11];
  const float* bfc3   = (const float*)d_in[12];
  float* out = (float*)d_out;
  char* ws = (char*)d_ws;
  const size_t MB = 1024 * 1024;

  __bf16* Wqkv_t = (__bf16*)(ws);            // 6 MB: [3072][1024]
  __bf16* Wo_t   = (__bf16*)(ws + 6 * MB);   // 2 MB
  __bf16* Wfc2_t = (__bf16*)(ws + 8 * MB);   // 8 MB: [4096][1024]
  __bf16* Wfc3_t = (__bf16*)(ws + 16 * MB);  // 8 MB: [1024][4096]
  __bf16* xb     = (__bf16*)(ws + 24 * MB);  // 8 MB; reused as attn_o
  __bf16* attn_o = xb;
  __bf16* qkv    = (__bf16*)(ws + 32 * MB);  // 24 MB; reused:
  float*  mlp_in = (float*)(ws + 32 * MB);   //   16 MB
  __bf16* h2     = (__bf16*)(ws + 48 * MB);  //   8 MB
  __bf16* qrb    = (__bf16*)(ws + 56 * MB);  // 8 MB; qr/kr/vt reused as hbuf
  __bf16* krb    = (__bf16*)(ws + 64 * MB);
  __bf16* vtb    = (__bf16*)(ws + 72 * MB);
  __bf16* hbuf   = (__bf16*)(ws + 56 * MB);  // 32 MB (after attention)

  const dim3 tb(32, 8);
  transpose_cast_qkv<<<dim3(32, 32, 3), tb, 0, stream>>>(Wq, Wk, Wv, Wqkv_t);
  transpose_cast<<<dim3(32, 32),  tb, 0, stream>>>(Wo,   Wo_t,   1024, 1024);
  transpose_cast<<<dim3(128, 32), tb, 0, stream>>>(Wfc2, Wfc2_t, 1024, 4096);
  transpose_cast<<<dim3(32, 128), tb, 0, stream>>>(Wfc3, Wfc3_t, 4096, 1024);

  ln_kernel<<<4096, 256, 0, stream>>>(inputs, ln1_g, ln1_b, xb);

  gemm_bf16<64, 1, EPI_BF16><<<dim3(24, 64), 256, 0, stream>>>(
      xb, Wqkv_t, qkv, nullptr, nullptr, nullptr, 4096, 3072, 1024);

  rope_qk<<<8192, 256, 0, stream>>>(qkv, qrb, krb);
  v_transpose<<<dim3(32, 16, 2), 256, 0, stream>>>(qkv, vtb);

  attn_kernel<<<dim3(16, 16, 2), 256, 0, stream>>>(qrb, krb, vtb, attn_o);

  // mlp_in = inputs + attn_o @ Wo  (init residual, then split-K atomic GEMM)
  init_out<<<4096, 256, 0, stream>>>(inputs, nullptr, mlp_in);
  gemm_bf16<64, 2, EPI_ATOMIC><<<dim3(8, 64, 2), 256, 0, stream>>>(
      attn_o, Wo_t, nullptr, mlp_in, nullptr, nullptr, 4096, 1024, 1024);

  ln_kernel<<<4096, 256, 0, stream>>>(mlp_in, ln2_g, ln2_b, h2);

  gemm_bf16<128, 1, EPI_GELU_BF16><<<dim3(32, 32), 256, 0, stream>>>(
      h2, Wfc2_t, hbuf, nullptr, bfc2, nullptr, 4096, 4096, 1024);

  // out = mlp_in + bfc3 + hbuf @ Wfc3  (init bias+res, then split-K atomic GEMM)
  init_out<<<4096, 256, 0, stream>>>(mlp_in, bfc3, out);
  gemm_bf16<64, 4, EPI_ATOMIC><<<dim3(8, 64, 4), 256, 0, stream>>>(
      hbuf, Wfc3_t, nullptr, out, nullptr, nullptr, 4096, 1024, 4096);
}

// Round 7
// 383.274 us; speedup vs baseline: 1.1508x; 1.1508x over previous
//
#include <hip/hip_runtime.h>
#include <cstdint>
#include <cstddef>

// ---------------- common types / helpers ----------------
typedef __bf16 bf16x8 __attribute__((ext_vector_type(8)));
typedef __bf16 bf16x4 __attribute__((ext_vector_type(4)));
typedef float  f32x4  __attribute__((ext_vector_type(4)));
typedef float  f32x16 __attribute__((ext_vector_type(16)));

__device__ __forceinline__ void load16_to_lds(const void* g, void* l) {
  __builtin_amdgcn_global_load_lds(
      (const __attribute__((address_space(1))) void*)g,
      (__attribute__((address_space(3))) void*)l, 16, 0, 0);
}

// ---------------- weight cast+transpose: f32 (K,N) -> bf16 (N,K) ----------------
__global__ __launch_bounds__(256) void transpose_cast(
    const float* __restrict__ src, __bf16* __restrict__ dst, int K, int N)
{
  __shared__ float tile[32][33];
  const int n0 = blockIdx.x * 32, k0 = blockIdx.y * 32;
  const int tx = threadIdx.x, ty = threadIdx.y; // (32,8)
#pragma unroll
  for (int i = 0; i < 32; i += 8)
    tile[ty + i][tx] = src[(size_t)(k0 + ty + i) * N + n0 + tx];
  __syncthreads();
#pragma unroll
  for (int i = 0; i < 32; i += 8)
    dst[(size_t)(n0 + ty + i) * K + k0 + tx] = (__bf16)tile[tx][ty + i];
}

// 3x 1024x1024 in one launch (z picks the weight)
__global__ __launch_bounds__(256) void transpose_cast_qkv(
    const float* __restrict__ s0, const float* __restrict__ s1,
    const float* __restrict__ s2, __bf16* __restrict__ dst)
{
  __shared__ float tile[32][33];
  const float* src = blockIdx.z == 0 ? s0 : blockIdx.z == 1 ? s1 : s2;
  __bf16* d = dst + (size_t)blockIdx.z * 1024 * 1024;
  const int n0 = blockIdx.x * 32, k0 = blockIdx.y * 32;
  const int tx = threadIdx.x, ty = threadIdx.y; // (32,8)
#pragma unroll
  for (int i = 0; i < 32; i += 8)
    tile[ty + i][tx] = src[(size_t)(k0 + ty + i) * 1024 + n0 + tx];
  __syncthreads();
#pragma unroll
  for (int i = 0; i < 32; i += 8)
    d[(size_t)(n0 + ty + i) * 1024 + k0 + tx] = (__bf16)tile[tx][ty + i];
}

// ---------------- LayerNorm: f32 row(1024) -> bf16 ----------------
__global__ __launch_bounds__(256) void ln_kernel(
    const float* __restrict__ x, const float* __restrict__ g,
    const float* __restrict__ bta, __bf16* __restrict__ out)
{
  const int row = blockIdx.x;
  const int t = threadIdx.x;
  const float4 v = ((const float4*)(x + (size_t)row * 1024))[t];
  float s  = v.x + v.y + v.z + v.w;
  float ss = v.x * v.x + v.y * v.y + v.z * v.z + v.w * v.w;
#pragma unroll
  for (int o = 32; o > 0; o >>= 1) { s += __shfl_down(s, o); ss += __shfl_down(ss, o); }
  __shared__ float rs[4], rss[4];
  const int w = t >> 6, l = t & 63;
  if (l == 0) { rs[w] = s; rss[w] = ss; }
  __syncthreads();
  s  = rs[0] + rs[1] + rs[2] + rs[3];
  ss = rss[0] + rss[1] + rss[2] + rss[3];
  const float mu = s * (1.0f / 1024.0f);
  const float var = ss * (1.0f / 1024.0f) - mu * mu;
  const float rstd = rsqrtf(var + 1e-5f);
  const float4 gg = ((const float4*)g)[t];
  const float4 bb = ((const float4*)bta)[t];
  __bf16* o = out + (size_t)row * 1024 + t * 4;
  o[0] = (__bf16)((v.x - mu) * rstd * gg.x + bb.x);
  o[1] = (__bf16)((v.y - mu) * rstd * gg.y + bb.y);
  o[2] = (__bf16)((v.z - mu) * rstd * gg.z + bb.z);
  o[3] = (__bf16)((v.w - mu) * rstd * gg.w + bb.w);
}

// ---------------- bf16 MFMA GEMM: C = A(MxK) * Bt(NxK)^T ----------------
// Double-buffered staging, ONE barrier per K-iteration (attention-v3
// structure): barrier -> frag ds_reads from buf p -> issue global_load_lds
// prefetch into buf 1-p -> MFMA. Prefetch is in flight during MFMA; the
// NEXT iteration's barrier drains it. Round-6 lesson: split-K atomics
// regressed (WRITE 16->65 MB, 8.4M L2 RMWs); the latency fix belongs in the
// K-loop structure, not in more blocks.
enum { EPI_BF16 = 0, EPI_RES_F32 = 1, EPI_GELU_BF16 = 2, EPI_BIAS_RES_F32 = 3 };

template <int TM, int EPI>
__global__ __launch_bounds__(256, 2) void gemm_bf16(
    const __bf16* __restrict__ A, const __bf16* __restrict__ Bt,
    __bf16* __restrict__ outb, float* __restrict__ outf,
    const float* __restrict__ bias, const float* __restrict__ res,
    int M, int N, int K)
{
  constexpr int MT = TM / 32;           // mt tiles per wave
  __shared__ __bf16 As[2][TM * 32];
  __shared__ __bf16 Bs[2][128 * 32];
  const int tid  = threadIdx.x;
  const int lane = tid & 63, w = tid >> 6;
  const int wm = w >> 1, wn = w & 1;
  const int quad = lane >> 4, l16 = lane & 15;
  const int m0 = blockIdx.y * TM, n0 = blockIdx.x * 128;

  f32x4 acc[MT][4] = {};
  const __bf16* Ag = A  + (size_t)m0 * K;
  const __bf16* Bg = Bt + (size_t)n0 * K;

  // prologue: stage tile 0 into buffer 0
#pragma unroll
  for (int r = 0; r < TM / 64; ++r) {
    const int c = r * 256 + tid;
    const int row = c >> 2, cc = (c & 3) * 8;
    load16_to_lds(Ag + (size_t)row * K + cc, &As[0][c * 8]);
  }
#pragma unroll
  for (int r = 0; r < 2; ++r) {
    const int c = r * 256 + tid;
    const int row = c >> 2, cc = (c & 3) * 8;
    load16_to_lds(Bg + (size_t)row * K + cc, &Bs[0][c * 8]);
  }

  const int nk = K >> 5;
  for (int kt = 0; kt < nk; ++kt) {
    __syncthreads();               // drains prefetch for tile kt (vmcnt before barrier)
    const int p = kt & 1;

    bf16x8 af[MT], bfr[4];
#pragma unroll
    for (int mt = 0; mt < MT; ++mt)
      af[mt] = *(const bf16x8*)&As[p][(wm * (TM / 2) + mt * 16 + l16) * 32 + quad * 8];
#pragma unroll
    for (int nt = 0; nt < 4; ++nt)
      bfr[nt] = *(const bf16x8*)&Bs[p][(wn * 64 + nt * 16 + l16) * 32 + quad * 8];

    if (kt + 1 < nk) {             // prefetch tile kt+1 into the other buffer
      const int k1 = (kt + 1) * 32;
#pragma unroll
      for (int r = 0; r < TM / 64; ++r) {
        const int c = r * 256 + tid;
        const int row = c >> 2, cc = (c & 3) * 8;
        load16_to_lds(Ag + (size_t)row * K + k1 + cc, &As[1 - p][c * 8]);
      }
#pragma unroll
      for (int r = 0; r < 2; ++r) {
        const int c = r * 256 + tid;
        const int row = c >> 2, cc = (c & 3) * 8;
        load16_to_lds(Bg + (size_t)row * K + k1 + cc, &Bs[1 - p][c * 8]);
      }
    }

#pragma unroll
    for (int mt = 0; mt < MT; ++mt)
#pragma unroll
      for (int nt = 0; nt < 4; ++nt)
        acc[mt][nt] = __builtin_amdgcn_mfma_f32_16x16x32_bf16(af[mt], bfr[nt], acc[mt][nt], 0, 0, 0);
  }

#pragma unroll
  for (int mt = 0; mt < MT; ++mt) {
#pragma unroll
    for (int nt = 0; nt < 4; ++nt) {
      const int col = n0 + wn * 64 + nt * 16 + l16;
#pragma unroll
      for (int i = 0; i < 4; ++i) {
        const int row = m0 + wm * (TM / 2) + mt * 16 + quad * 4 + i;
        float v = acc[mt][nt][i];
        const size_t idx = (size_t)row * N + col;
        if (EPI == EPI_BF16) {
          outb[idx] = (__bf16)v;
        } else if (EPI == EPI_RES_F32) {
          outf[idx] = v + res[idx];
        } else if (EPI == EPI_GELU_BF16) {
          v += bias[col];
          outb[idx] = (__bf16)(0.5f * v * (1.0f + erff(v * 0.70710678118f)));
        } else {
          v += bias[col];
          outf[idx] = v + res[idx];
        }
      }
    }
  }
}

// ---------------- RoPE for q,k: qkv(4096x3072) -> qr,kr [b][h][s][d] ----------------
__global__ __launch_bounds__(256) void rope_qk(
    const __bf16* __restrict__ qkv, __bf16* __restrict__ qr, __bf16* __restrict__ kr)
{
  const int idx = blockIdx.x * 256 + threadIdx.x; // (b,s,h,d2)
  const int d2 = idx & 31;
  const int h  = (idx >> 5) & 15;
  const int bs = idx >> 9;       // b*2048+s
  const int s  = bs & 2047;
  const int b  = bs >> 11;
  const float inv_freq = exp2f(-((float)d2 * (1.0f / 32.0f)) * 13.2877123795f); // log2(1e4)
  const float ang = (float)s * inv_freq;
  const float c = cosf(ang), sn = sinf(ang);
  const __bf16* qp = qkv + (size_t)bs * 3072 + h * 64 + 2 * d2;
  const __bf16* kp = qp + 1024;
  const float q0 = (float)qp[0], q1 = (float)qp[1];
  const float k0 = (float)kp[0], k1 = (float)kp[1];
  const size_t o = ((size_t)(b * 16 + h) * 2048 + s) * 64 + 2 * d2;
  qr[o]     = (__bf16)(q0 * c - q1 * sn);
  qr[o + 1] = (__bf16)(q1 * c + q0 * sn);
  kr[o]     = (__bf16)(k0 * c - k1 * sn);
  kr[o + 1] = (__bf16)(k1 * c + k0 * sn);
}

// ---------------- V transpose: qkv v-cols -> vt [b][h][d][s] ----------------
__global__ __launch_bounds__(256) void v_transpose(
    const __bf16* __restrict__ qkv, __bf16* __restrict__ vt)
{
  __shared__ __bf16 t[64][72];
  const int st = blockIdx.x, h = blockIdx.y, b = blockIdx.z;
  const int tx = threadIdx.x & 63, ty = threadIdx.x >> 6; // 64x4
  const int s0 = st * 64;
  const __bf16* src = qkv + ((size_t)(b * 2048 + s0)) * 3072 + 2048 + h * 64;
#pragma unroll
  for (int i = 0; i < 64; i += 4)
    t[ty + i][tx] = src[(size_t)(ty + i) * 3072 + tx];
  __syncthreads();
  __bf16* dst = vt + ((size_t)(b * 16 + h) * 64) * 2048 + s0;
#pragma unroll
  for (int i = 0; i < 64; i += 4)
    dst[(size_t)(ty + i) * 2048 + tx] = t[tx][ty + i];
}

// ---------------- flash attention v3: 32x32x16 MFMA, S^T orientation --------
__global__ __launch_bounds__(256, 2) void attn_kernel(
    const __bf16* __restrict__ qr, const __bf16* __restrict__ kr,
    const __bf16* __restrict__ vt, __bf16* __restrict__ attn_o)
{
  constexpr int S = 2048, DH = 64, NH = 16, BQ = 128, BKK = 64;
  __shared__ __align__(16) __bf16 smem[24576];  // 48 KB
  __bf16* Qs   = smem;                       // [128][64] swizzled; -> per-wave Pb
  __bf16* Ksb  = smem + 8192;                // 2 x [64][64] swizzled
  __bf16* Vtsb = smem + 16384;               // 2 x [64][64] swizzled

  const int tid = threadIdx.x;
  const int lane = tid & 63, w = tid >> 6;
  const int l32 = lane & 31, half = lane >> 5;
  const int qt = blockIdx.x, h = blockIdx.y, b = blockIdx.z;
  const int bh = b * NH + h;
  const __bf16* Q  = qr + ((size_t)bh * S + qt * BQ) * DH;
  const __bf16* Kp = kr + (size_t)bh * S * DH;
  const __bf16* Vp = vt + (size_t)bh * DH * S;
  __bf16* Pb = Qs + w * 2048;                // wave-local [32][64] swizzled

#pragma unroll
  for (int r4 = 0; r4 < 4; ++r4) {
    const int c = r4 * 256 + tid;
    const int r = c >> 3, cb = c & 7;
    load16_to_lds(Q + (size_t)r * DH + ((cb ^ (r & 7)) * 8), &Qs[c * 8]);
  }
#pragma unroll
  for (int r2 = 0; r2 < 2; ++r2) {
    const int c = r2 * 256 + tid;
    const int r = c >> 3, cb = c & 7;
    const int cg = (cb ^ (r & 7)) * 8;
    load16_to_lds(Kp + (size_t)r * DH + cg, &Ksb[c * 8]);
    load16_to_lds(Vp + (size_t)r * S + cg, &Vtsb[c * 8]);
  }
  __syncthreads();

  bf16x8 qfB[4];
  {
    const int row = w * 32 + l32;
#pragma unroll
    for (int c = 0; c < 4; ++c)
      qfB[c] = *(const bf16x8*)&Qs[row * 64 + (((2 * c + half) ^ (row & 7)) * 8)];
  }

  float mreg = -3.0e38f, lreg = 0.0f;
  f32x16 oacc[2] = {};

  for (int kt = 0; kt < S / BKK; ++kt) {
    if (kt) __syncthreads();
    const __bf16* Ks  = Ksb  + (kt & 1) * 4096;
    const __bf16* Vts = Vtsb + (kt & 1) * 4096;

    bf16x8 kf[2][4], vf[2][4];
#pragma unroll
    for (int t = 0; t < 2; ++t) {
      const int row = 32 * t + l32;
#pragma unroll
      for (int c = 0; c < 4; ++c)
        kf[t][c] = *(const bf16x8*)&Ks[row * 64 + (((2 * c + half) ^ (l32 & 7)) * 8)];
    }
#pragma unroll
    for (int v = 0; v < 2; ++v) {
      const int row = 32 * v + l32;
#pragma unroll
      for (int c = 0; c < 4; ++c)
        vf[v][c] = *(const bf16x8*)&Vts[row * 64 + (((2 * c + half) ^ (l32 & 7)) * 8)];
    }

    if (kt + 1 < S / BKK) {
      __bf16* Kn = Ksb  + ((kt + 1) & 1) * 4096;
      __bf16* Vn = Vtsb + ((kt + 1) & 1) * 4096;
      const size_t kk1 = (size_t)(kt + 1) * BKK;
#pragma unroll
      for (int r2 = 0; r2 < 2; ++r2) {
        const int c = r2 * 256 + tid;
        const int r = c >> 3, cb = c & 7;
        const int cg = (cb ^ (r & 7)) * 8;
        load16_to_lds(Kp + (kk1 + r) * DH + cg, &Kn[c * 8]);
        load16_to_lds(Vp + (size_t)r * S + kk1 + cg, &Vn[c * 8]);
      }
    }

    f32x16 sa[2] = {};
#pragma unroll
    for (int t = 0; t < 2; ++t)
#pragma unroll
      for (int c = 0; c < 4; ++c)
        sa[t] = __builtin_amdgcn_mfma_f32_32x32x16_bf16(kf[t][c], qfB[c], sa[t], 0, 0, 0);

    float mx = -3.0e38f;
#pragma unroll
    for (int t = 0; t < 2; ++t)
#pragma unroll
      for (int r = 0; r < 16; ++r) { sa[t][r] *= 0.125f; mx = fmaxf(mx, sa[t][r]); }
    mx = fmaxf(mx, __shfl_xor(mx, 32));
    const float mnew = fmaxf(mreg, mx);
    const float alpha = __expf(mreg - mnew);
    mreg = mnew;
    float sum = 0.0f;
#pragma unroll
    for (int t = 0; t < 2; ++t)
#pragma unroll
      for (int r = 0; r < 16; ++r) {
        const float p = __expf(sa[t][r] - mnew);
        sa[t][r] = p;
        sum += p;
      }
    sum += __shfl_xor(sum, 32);
    lreg = lreg * alpha + sum;
#pragma unroll
    for (int v = 0; v < 2; ++v)
#pragma unroll
      for (int r = 0; r < 16; ++r) oacc[v][r] *= alpha;

#pragma unroll
    for (int t = 0; t < 2; ++t)
#pragma unroll
      for (int g = 0; g < 4; ++g) {
        bf16x4 pv;
#pragma unroll
        for (int i = 0; i < 4; ++i) pv[i] = (__bf16)sa[t][4 * g + i];
        const int kc = 4 * t + g;
        *(bf16x4*)&Pb[l32 * 64 + ((kc ^ (l32 & 7)) * 8) + 4 * half] = pv;
      }

    bf16x8 pf[4];
#pragma unroll
    for (int c = 0; c < 4; ++c)
      pf[c] = *(const bf16x8*)&Pb[l32 * 64 + (((2 * c + half) ^ (l32 & 7)) * 8)];
#pragma unroll
    for (int v = 0; v < 2; ++v)
#pragma unroll
      for (int c = 0; c < 4; ++c)
        oacc[v] = __builtin_amdgcn_mfma_f32_32x32x16_bf16(vf[v][c], pf[c], oacc[v], 0, 0, 0);
  }

  const float linv = 1.0f / lreg;
#pragma unroll
  for (int v = 0; v < 2; ++v)
#pragma unroll
    for (int g = 0; g < 4; ++g) {
      bf16x4 ov;
#pragma unroll
      for (int i = 0; i < 4; ++i) ov[i] = (__bf16)(oacc[v][4 * g + i] * linv);
      const int dc = 4 * v + g;
      *(bf16x4*)&Pb[l32 * 64 + ((dc ^ (l32 & 7)) * 8) + 4 * half] = ov;
    }
#pragma unroll
  for (int cc = 0; cc < 4; ++cc) {
    const int c = cc * 64 + lane;
    const int r = c >> 3, g = c & 7;
    const bf16x8 od = *(const bf16x8*)&Pb[r * 64 + ((g ^ (r & 7)) * 8)];
    const int srow = qt * BQ + w * 32 + r;
    *(bf16x8*)&attn_o[((size_t)b * S + srow) * 1024 + h * 64 + g * 8] = od;
  }
}

// ---------------- launch ----------------
extern "C" void kernel_launch(void* const* d_in, const int* in_sizes, int n_in,
                              void* d_out, int out_size, void* d_ws, size_t ws_size,
                              hipStream_t stream) {
  const float* inputs = (const float*)d_in[0];
  const float* ln1_g  = (const float*)d_in[1];
  const float* ln1_b  = (const float*)d_in[2];
  const float* Wq     = (const float*)d_in[3];
  const float* Wk     = (const float*)d_in[4];
  const float* Wv     = (const float*)d_in[5];
  const float* Wo     = (const float*)d_in[6];
  const float* ln2_g  = (const float*)d_in[7];
  const float* ln2_b  = (const float*)d_in[8];
  const float* Wfc2   = (const float*)d_in[9];
  const float* bfc2   = (const float*)d_in[10];
  const float* Wfc3   = (const float*)d_in[11];
  const float* bfc3   = (const float*)d_in[12];
  float* out = (float*)d_out;
  char* ws = (char*)d_ws;
  const size_t MB = 1024 * 1024;

  __bf16* Wqkv_t = (__bf16*)(ws);            // 6 MB: [3072][1024]
  __bf16* Wo_t   = (__bf16*)(ws + 6 * MB);   // 2 MB
  __bf16* Wfc2_t = (__bf16*)(ws + 8 * MB);   // 8 MB: [4096][1024]
  __bf16* Wfc3_t = (__bf16*)(ws + 16 * MB);  // 8 MB: [1024][4096]
  __bf16* xb     = (__bf16*)(ws + 24 * MB);  // 8 MB; reused as attn_o
  __bf16* attn_o = xb;
  __bf16* qkv    = (__bf16*)(ws + 32 * MB);  // 24 MB; reused:
  float*  mlp_in = (float*)(ws + 32 * MB);   //   16 MB
  __bf16* h2     = (__bf16*)(ws + 48 * MB);  //   8 MB
  __bf16* qrb    = (__bf16*)(ws + 56 * MB);  // 8 MB; qr/kr/vt reused as hbuf
  __bf16* krb    = (__bf16*)(ws + 64 * MB);
  __bf16* vtb    = (__bf16*)(ws + 72 * MB);
  __bf16* hbuf   = (__bf16*)(ws + 56 * MB);  // 32 MB (after attention)

  const dim3 tb(32, 8);
  transpose_cast_qkv<<<dim3(32, 32, 3), tb, 0, stream>>>(Wq, Wk, Wv, Wqkv_t);
  transpose_cast<<<dim3(32, 32),  tb, 0, stream>>>(Wo,   Wo_t,   1024, 1024);
  transpose_cast<<<dim3(128, 32), tb, 0, stream>>>(Wfc2, Wfc2_t, 1024, 4096);
  transpose_cast<<<dim3(32, 128), tb, 0, stream>>>(Wfc3, Wfc3_t, 4096, 1024);

  ln_kernel<<<4096, 256, 0, stream>>>(inputs, ln1_g, ln1_b, xb);

  gemm_bf16<64, EPI_BF16><<<dim3(24, 64), 256, 0, stream>>>(
      xb, Wqkv_t, qkv, nullptr, nullptr, nullptr, 4096, 3072, 1024);

  rope_qk<<<8192, 256, 0, stream>>>(qkv, qrb, krb);
  v_transpose<<<dim3(32, 16, 2), 256, 0, stream>>>(qkv, vtb);

  attn_kernel<<<dim3(16, 16, 2), 256, 0, stream>>>(qrb, krb, vtb, attn_o);

  gemm_bf16<64, EPI_RES_F32><<<dim3(8, 64), 256, 0, stream>>>(
      attn_o, Wo_t, nullptr, mlp_in, nullptr, inputs, 4096, 1024, 1024);

  ln_kernel<<<4096, 256, 0, stream>>>(mlp_in, ln2_g, ln2_b, h2);

  gemm_bf16<128, EPI_GELU_BF16><<<dim3(32, 32), 256, 0, stream>>>(
      h2, Wfc2_t, hbuf, nullptr, bfc2, nullptr, 4096, 4096, 1024);

  gemm_bf16<64, EPI_BIAS_RES_F32><<<dim3(8, 64), 256, 0, stream>>>(
      hbuf, Wfc3_t, nullptr, out, bfc3, mlp_in, 4096, 1024, 4096);
}